// Round 6
// baseline (247.532 us; speedup 1.0000x reference)
//
#include <hip/hip_runtime.h>
#include <hip/hip_bf16.h>

typedef __attribute__((ext_vector_type(8))) short short8;
typedef __attribute__((ext_vector_type(4))) float f32x4;

#define EPW 128   // edges per wave in k_spmm

__device__ __forceinline__ unsigned short f2bf(float x) {
    unsigned int u = __float_as_uint(x);
    unsigned int lsb = (u >> 16) & 1u;
    u += 0x7fffu + lsb;                    // round-to-nearest-even
    return (unsigned short)(u >> 16);
}

__device__ __forceinline__ float bf2f(unsigned int b16) {
    return __uint_as_float(b16 << 16);
}

__device__ __forceinline__ short8 pack8(f32x4 a, f32x4 b) {
    short8 r;
    r[0] = (short)f2bf(a.x); r[1] = (short)f2bf(a.y);
    r[2] = (short)f2bf(a.z); r[3] = (short)f2bf(a.w);
    r[4] = (short)f2bf(b.x); r[5] = (short)f2bf(b.y);
    r[6] = (short)f2bf(b.z); r[7] = (short)f2bf(b.w);
    return r;
}

// Standalone init (fallback path): out[n][c] = bias[c]
__global__ __launch_bounds__(256) void k_init(const float* __restrict__ bias,
                                              float* __restrict__ out, long total4) {
    long i4 = (long)blockIdx.x * 256 + threadIdx.x;
    if (i4 < total4) {
        const f32x4* b4 = (const f32x4*)bias;
        ((f32x4*)out)[i4] = b4[i4 & 15];
    }
}

// Fused: blocks [0,gblocks) compute G = (feat @ W.T) in bf16 via MFMA;
// blocks [gblocks, ...) broadcast bias into out.
// NOTE: out init must be a PLAIN store — NT store streamed it to HBM and made
// every later atomic flush RMW against HBM (R4: WRITE_SIZE doubled, +22 us).
__global__ __launch_bounds__(256) void k_setup(const float* __restrict__ feat,
                                               const float* __restrict__ W,
                                               const float* __restrict__ bias,
                                               unsigned short* __restrict__ G,
                                               float* __restrict__ out,
                                               int N, int gblocks) {
    if ((int)blockIdx.x >= gblocks) {
        long i4 = (long)(blockIdx.x - gblocks) * 256 + threadIdx.x;
        long total4 = (long)N * 16;            // N*64 floats / 4
        if (i4 < total4) {
            const f32x4* b4 = (const f32x4*)bias;
            ((f32x4*)out)[i4] = b4[i4 & 15];   // plain store: stay dirty in L2
        }
        return;
    }

    int wave = blockIdx.x * 4 + (threadIdx.x >> 6);
    int lane = threadIdx.x & 63;
    int m0 = wave * 16;
    if (m0 >= N) return;
    int n = lane & 15;
    int quad = lane >> 4;

    // B fragments: B[k][c0+n] = W[c0+n][k]; k = ks*32 + quad*8 + j
    short8 bf[4][2];
#pragma unroll
    for (int ct = 0; ct < 4; ++ct)
#pragma unroll
        for (int ks = 0; ks < 2; ++ks) {
            const f32x4* wp = (const f32x4*)(W + (size_t)(ct * 16 + n) * 64 + ks * 32 + quad * 8);
            f32x4 w0 = wp[0];
            f32x4 w1 = wp[1];
            bf[ct][ks] = pack8(w0, w1);
        }

    // A fragments: A[m0+n][k]  (NT load: feat read exactly once)
    int mrow = m0 + n; if (mrow >= N) mrow = N - 1;
    short8 af[2];
#pragma unroll
    for (int ks = 0; ks < 2; ++ks) {
        const f32x4* ap = (const f32x4*)(feat + (size_t)mrow * 64 + ks * 32 + quad * 8);
        f32x4 a0 = __builtin_nontemporal_load(ap);
        f32x4 a1 = __builtin_nontemporal_load(ap + 1);
        af[ks] = pack8(a0, a1);
    }

    f32x4 acc[4];
#pragma unroll
    for (int ct = 0; ct < 4; ++ct) {
        acc[ct] = (f32x4){0.f, 0.f, 0.f, 0.f};
#pragma unroll
        for (int ks = 0; ks < 2; ++ks)
            acc[ct] = __builtin_amdgcn_mfma_f32_16x16x32_bf16(af[ks], bf[ct][ks], acc[ct], 0, 0, 0);
    }

    // D layout: col = lane&15 (=n), row = quad*4 + reg. Plain stores: G is
    // re-read by k_spmm, keep it in L2/L3.
#pragma unroll
    for (int ct = 0; ct < 4; ++ct)
#pragma unroll
        for (int r = 0; r < 4; ++r) {
            int rowm = m0 + quad * 4 + r;
            if (rowm < N)
                G[(size_t)rowm * 64 + ct * 16 + n] = f2bf(acc[ct][r]);
        }
}

// SpMM: out[row] += val * G[col]. Sorted rows.
// - wave id made uniform via readfirstlane -> metadata addresses are
//   wave-uniform -> compiler emits scalar s_load (zero VALU, scalar pipe).
// - gathers: SGPR base + invariant lane offset (saddr form), 16 in flight.
// - sorted rows => only the wave's FIRST and LAST rows can be shared with
//   neighboring waves: those flush via atomicAdd; interior rows flush with a
//   plain coalesced store out[row] = bias + acc (init value is overwritten).
__global__ __launch_bounds__(256) void k_spmm(const unsigned short* __restrict__ G,
                                              const int* __restrict__ erow,
                                              const int* __restrict__ ecol,
                                              const float* __restrict__ evalv,
                                              const float* __restrict__ bias,
                                              float* __restrict__ out, int E) {
    int wid = __builtin_amdgcn_readfirstlane(blockIdx.x * 4 + (threadIdx.x >> 6));
    int lane = threadIdx.x & 63;
    long e0 = (long)wid * EPW;
    if (e0 >= E) return;
    long rem = E - e0;
    int nav = rem < EPW ? (int)rem : EPW;     // uniform

    float blane = bias[lane];
    int cur = erow[e0];                        // uniform -> s_load
    float acc = 0.f;
    bool first = true;                         // first flush may be shared

#define CHUNK16(JB)                                                            \
    {                                                                          \
        int cc[16];                                                            \
        _Pragma("unroll")                                                      \
        for (int u = 0; u < 16; ++u) cc[u] = ecol[e0 + (JB) + u];              \
        unsigned short gv[16];                                                 \
        _Pragma("unroll")                                                      \
        for (int u = 0; u < 16; ++u)                                           \
            gv[u] = G[((size_t)(unsigned)cc[u] << 6) | (unsigned)lane];        \
        _Pragma("unroll")                                                      \
        for (int u = 0; u < 16; ++u) {                                         \
            int r = erow[e0 + (JB) + u];                                       \
            float v = evalv[e0 + (JB) + u];                                    \
            if (r != cur) {                                                    \
                if (first) {                                                   \
                    atomicAdd(out + ((size_t)(unsigned)cur << 6) + lane, acc); \
                    first = false;                                             \
                } else {                                                       \
                    out[((size_t)(unsigned)cur << 6) + lane] = blane + acc;    \
                }                                                              \
                acc = 0.f;                                                     \
                cur = r;                                                       \
            }                                                                  \
            acc = fmaf(v, bf2f(gv[u]), acc);                                   \
        }                                                                      \
    }

    if (nav == EPW) {
#pragma unroll
        for (int jb = 0; jb < EPW; jb += 16) CHUNK16(jb)
    } else {
        int j = 0;
        for (; j + 16 <= nav; j += 16) CHUNK16(j)
        for (; j < nav; ++j) {
            int r = erow[e0 + j];
            int c = ecol[e0 + j];
            float v = evalv[e0 + j];
            float g = bf2f(G[((size_t)(unsigned)c << 6) | (unsigned)lane]);
            if (r != cur) {
                if (first) {
                    atomicAdd(out + ((size_t)(unsigned)cur << 6) + lane, acc);
                    first = false;
                } else {
                    out[((size_t)(unsigned)cur << 6) + lane] = blane + acc;
                }
                acc = 0.f;
                cur = r;
            }
            acc = fmaf(v, g, acc);
        }
    }
#undef CHUNK16

    // last row may be shared with the next wave -> always atomic
    atomicAdd(out + ((size_t)(unsigned)cur << 6) + lane, acc);
}

// Fallback if ws too small: fused f32 gather + shfl transform at flush.
__global__ __launch_bounds__(256) void k_fused(const float* __restrict__ feat,
                                               const int* __restrict__ erow,
                                               const int* __restrict__ ecol,
                                               const float* __restrict__ evalv,
                                               const float* __restrict__ W,
                                               float* __restrict__ out,
                                               int E, int epw) {
    __shared__ float Wt[64 * 64];
    for (int i = threadIdx.x; i < 4096; i += 256) {
        int c = i >> 6, f = i & 63;
        Wt[f * 64 + c] = W[i];
    }
    __syncthreads();

    int wave = blockIdx.x * 4 + (threadIdx.x >> 6);
    int lane = threadIdx.x & 63;
    long e0 = (long)wave * epw;
    if (e0 >= E) return;
    long e1 = e0 + epw; if (e1 > E) e1 = E;

    int cur = erow[e0];
    float acc = 0.f;
    for (long e = e0; e < e1; ++e) {
        int r = erow[e];
        int c = ecol[e];
        float v = evalv[e];
        float g = feat[((size_t)c << 6) | lane];
        if (r != cur) {
            float res = 0.f;
#pragma unroll
            for (int f = 0; f < 64; ++f)
                res += __shfl(acc, f, 64) * Wt[f * 64 + lane];
            atomicAdd(out + ((size_t)cur << 6) + lane, res);
            acc = 0.f;
            cur = r;
        }
        acc += v * g;
    }
    {
        float res = 0.f;
#pragma unroll
        for (int f = 0; f < 64; ++f)
            res += __shfl(acc, f, 64) * Wt[f * 64 + lane];
        atomicAdd(out + ((size_t)cur << 6) + lane, res);
    }
}

extern "C" void kernel_launch(void* const* d_in, const int* in_sizes, int n_in,
                              void* d_out, int out_size, void* d_ws, size_t ws_size,
                              hipStream_t stream) {
    const float* feat  = (const float*)d_in[0];
    const int*   erow  = (const int*)d_in[1];
    const int*   ecol  = (const int*)d_in[2];
    const float* evalv = (const float*)d_in[3];
    const float* W     = (const float*)d_in[4];
    const float* bias  = (const float*)d_in[5];
    float* out = (float*)d_out;

    int N = in_sizes[0] / 64;
    int E = in_sizes[1];

    size_t need = (size_t)N * 64 * sizeof(unsigned short);
    if (ws_size >= need) {
        unsigned short* G = (unsigned short*)d_ws;
        int tiles = (N + 15) / 16;
        int gblocks = (tiles + 3) / 4;
        long total4 = (long)N * 16;
        int iblocks = (int)((total4 + 255) / 256);
        k_setup<<<gblocks + iblocks, 256, 0, stream>>>(feat, W, bias, G, out, N, gblocks);

        int nwaves = (E + EPW - 1) / EPW;
        int nblocks = (nwaves + 3) / 4;
        k_spmm<<<nblocks, 256, 0, stream>>>(G, erow, ecol, evalv, bias, out, E);
    } else {
        long total4 = (long)N * 16;
        k_init<<<(int)((total4 + 255) / 256), 256, 0, stream>>>(bias, out, total4);
        int epw = (E + 8191) / 8192;
        if (epw < 32) epw = 32;
        int nwaves = (E + epw - 1) / epw;
        int nblocks = (nwaves + 3) / 4;
        k_fused<<<nblocks, 256, 0, stream>>>(feat, erow, ecol, evalv, W, out, E, epw);
    }
}

// Round 7
// 141.614 us; speedup vs baseline: 1.7479x; 1.7479x over previous
//
#include <hip/hip_runtime.h>
#include <hip/hip_bf16.h>

typedef __attribute__((ext_vector_type(8))) short short8;
typedef __attribute__((ext_vector_type(4))) float f32x4;

__device__ __forceinline__ unsigned short f2bf(float x) {
    unsigned int u = __float_as_uint(x);
    unsigned int lsb = (u >> 16) & 1u;
    u += 0x7fffu + lsb;                    // round-to-nearest-even
    return (unsigned short)(u >> 16);
}

__device__ __forceinline__ float bf2f(unsigned int b16) {
    return __uint_as_float(b16 << 16);
}

__device__ __forceinline__ short8 pack8(f32x4 a, f32x4 b) {
    short8 r;
    r[0] = (short)f2bf(a.x); r[1] = (short)f2bf(a.y);
    r[2] = (short)f2bf(a.z); r[3] = (short)f2bf(a.w);
    r[4] = (short)f2bf(b.x); r[5] = (short)f2bf(b.y);
    r[6] = (short)f2bf(b.z); r[7] = (short)f2bf(b.w);
    return r;
}

// Standalone init (fallback path): out[n][c] = bias[c]
__global__ __launch_bounds__(256) void k_init(const float* __restrict__ bias,
                                              float* __restrict__ out, long total4) {
    long i4 = (long)blockIdx.x * 256 + threadIdx.x;
    if (i4 < total4) {
        const f32x4* b4 = (const f32x4*)bias;
        ((f32x4*)out)[i4] = b4[i4 & 15];
    }
}

// Fused: blocks [0,gblocks) compute G = (feat @ W.T) in bf16 via MFMA;
// blocks [gblocks, ...) broadcast bias into out.
// NOTE: out init must be a PLAIN store — NT store streamed it to HBM and made
// every later atomic flush RMW against HBM (R4: WRITE_SIZE doubled, +22 us).
__global__ __launch_bounds__(256) void k_setup(const float* __restrict__ feat,
                                               const float* __restrict__ W,
                                               const float* __restrict__ bias,
                                               unsigned short* __restrict__ G,
                                               float* __restrict__ out,
                                               int N, int gblocks) {
    if ((int)blockIdx.x >= gblocks) {
        long i4 = (long)(blockIdx.x - gblocks) * 256 + threadIdx.x;
        long total4 = (long)N * 16;            // N*64 floats / 4
        if (i4 < total4) {
            const f32x4* b4 = (const f32x4*)bias;
            ((f32x4*)out)[i4] = b4[i4 & 15];   // plain store: stay dirty in L2
        }
        return;
    }

    int wave = blockIdx.x * 4 + (threadIdx.x >> 6);
    int lane = threadIdx.x & 63;
    int m0 = wave * 16;
    if (m0 >= N) return;
    int n = lane & 15;
    int quad = lane >> 4;

    // B fragments: B[k][c0+n] = W[c0+n][k]; k = ks*32 + quad*8 + j
    short8 bf[4][2];
#pragma unroll
    for (int ct = 0; ct < 4; ++ct)
#pragma unroll
        for (int ks = 0; ks < 2; ++ks) {
            const f32x4* wp = (const f32x4*)(W + (size_t)(ct * 16 + n) * 64 + ks * 32 + quad * 8);
            f32x4 w0 = wp[0];
            f32x4 w1 = wp[1];
            bf[ct][ks] = pack8(w0, w1);
        }

    // A fragments: A[m0+n][k]  (NT load: feat read exactly once)
    int mrow = m0 + n; if (mrow >= N) mrow = N - 1;
    short8 af[2];
#pragma unroll
    for (int ks = 0; ks < 2; ++ks) {
        const f32x4* ap = (const f32x4*)(feat + (size_t)mrow * 64 + ks * 32 + quad * 8);
        f32x4 a0 = __builtin_nontemporal_load(ap);
        f32x4 a1 = __builtin_nontemporal_load(ap + 1);
        af[ks] = pack8(a0, a1);
    }

    f32x4 acc[4];
#pragma unroll
    for (int ct = 0; ct < 4; ++ct) {
        acc[ct] = (f32x4){0.f, 0.f, 0.f, 0.f};
#pragma unroll
        for (int ks = 0; ks < 2; ++ks)
            acc[ct] = __builtin_amdgcn_mfma_f32_16x16x32_bf16(af[ks], bf[ct][ks], acc[ct], 0, 0, 0);
    }

    // D layout: col = lane&15 (=n), row = quad*4 + reg. Plain stores: G is
    // re-read by k_spmm, keep it in L2/L3.
#pragma unroll
    for (int ct = 0; ct < 4; ++ct)
#pragma unroll
        for (int r = 0; r < 4; ++r) {
            int rowm = m0 + quad * 4 + r;
            if (rowm < N)
                G[(size_t)rowm * 64 + ct * 16 + n] = f2bf(acc[ct][r]);
        }
}

// SpMM: out[row] += val * G[col]. Sorted rows.
// R5 proven structure: per 64-edge chunk one coalesced VECTOR load per
// metadata array (NT), then readlane-broadcast -> (r,c,v) in SGPRs: scalar
// flush branch, SGPR gather base; 16 gathers in flight before consume.
// R7 addition: sorted rows => only the wave's FIRST and LAST row values can
// be shared with neighboring waves. Those flush via atomicAdd; interior rows
// flush with a full-line coalesced store out[row] = bias + acc (overwrites
// the bias init; row exclusively owned by this wave).
__global__ __launch_bounds__(256) void k_spmm(const unsigned short* __restrict__ G,
                                              const int* __restrict__ erow,
                                              const int* __restrict__ ecol,
                                              const float* __restrict__ evalv,
                                              const float* __restrict__ bias,
                                              float* __restrict__ out,
                                              int E, int cpw) {
    int wave = blockIdx.x * 4 + (threadIdx.x >> 6);
    int lane = threadIdx.x & 63;
    long base0 = (long)wave * cpw * 64;
    if (base0 >= E) return;

    float blane = bias[lane];
    int cur = __builtin_amdgcn_readfirstlane(erow[base0]);
    float acc = 0.f;
    bool first = true;             // first flushed row may be shared w/ prev wave

    for (int ch = 0; ch < cpw; ++ch) {
        long base = base0 + (long)ch * 64;
        if (base >= E) break;
        long idx = base + lane;
        long cidx = idx < E ? idx : (long)(E - 1);
        int rv = __builtin_nontemporal_load(erow + cidx);
        int cv = __builtin_nontemporal_load(ecol + cidx);
        float vf = (idx < E) ? __builtin_nontemporal_load(evalv + cidx) : 0.f;
        int vv = __float_as_int(vf);

#pragma unroll
        for (int j0 = 0; j0 < 64; j0 += 16) {
            float g[16];
#pragma unroll
            for (int u = 0; u < 16; ++u) {
                int c = __builtin_amdgcn_readlane(cv, j0 + u);   // SGPR
                g[u] = bf2f(G[((size_t)(unsigned)c << 6) | (unsigned)lane]);
            }
#pragma unroll
            for (int u = 0; u < 16; ++u) {
                int r = __builtin_amdgcn_readlane(rv, j0 + u);   // SGPR
                float v = __int_as_float(__builtin_amdgcn_readlane(vv, j0 + u));
                if (r != cur) {                                   // scalar branch
                    if (first) {
                        atomicAdd(out + ((size_t)(unsigned)cur << 6) + lane, acc);
                        first = false;
                    } else {
                        out[((size_t)(unsigned)cur << 6) + lane] = blane + acc;
                    }
                    acc = 0.f;
                    cur = r;
                }
                acc = fmaf(v, g[u], acc);
            }
        }
    }
    // last row may be shared with the next wave -> always atomic
    atomicAdd(out + ((size_t)(unsigned)cur << 6) + lane, acc);
}

// Fallback if ws too small: fused f32 gather + shfl transform at flush.
__global__ __launch_bounds__(256) void k_fused(const float* __restrict__ feat,
                                               const int* __restrict__ erow,
                                               const int* __restrict__ ecol,
                                               const float* __restrict__ evalv,
                                               const float* __restrict__ W,
                                               float* __restrict__ out,
                                               int E, int epw) {
    __shared__ float Wt[64 * 64];
    for (int i = threadIdx.x; i < 4096; i += 256) {
        int c = i >> 6, f = i & 63;
        Wt[f * 64 + c] = W[i];
    }
    __syncthreads();

    int wave = blockIdx.x * 4 + (threadIdx.x >> 6);
    int lane = threadIdx.x & 63;
    long e0 = (long)wave * epw;
    if (e0 >= E) return;
    long e1 = e0 + epw; if (e1 > E) e1 = E;

    int cur = erow[e0];
    float acc = 0.f;
    for (long e = e0; e < e1; ++e) {
        int r = erow[e];
        int c = ecol[e];
        float v = evalv[e];
        float g = feat[((size_t)c << 6) | lane];
        if (r != cur) {
            float res = 0.f;
#pragma unroll
            for (int f = 0; f < 64; ++f)
                res += __shfl(acc, f, 64) * Wt[f * 64 + lane];
            atomicAdd(out + ((size_t)cur << 6) + lane, res);
            acc = 0.f;
            cur = r;
        }
        acc += v * g;
    }
    {
        float res = 0.f;
#pragma unroll
        for (int f = 0; f < 64; ++f)
            res += __shfl(acc, f, 64) * Wt[f * 64 + lane];
        atomicAdd(out + ((size_t)cur << 6) + lane, res);
    }
}

extern "C" void kernel_launch(void* const* d_in, const int* in_sizes, int n_in,
                              void* d_out, int out_size, void* d_ws, size_t ws_size,
                              hipStream_t stream) {
    const float* feat  = (const float*)d_in[0];
    const int*   erow  = (const int*)d_in[1];
    const int*   ecol  = (const int*)d_in[2];
    const float* evalv = (const float*)d_in[3];
    const float* W     = (const float*)d_in[4];
    const float* bias  = (const float*)d_in[5];
    float* out = (float*)d_out;

    int N = in_sizes[0] / 64;
    int E = in_sizes[1];

    size_t need = (size_t)N * 64 * sizeof(unsigned short);
    if (ws_size >= need) {
        unsigned short* G = (unsigned short*)d_ws;
        int tiles = (N + 15) / 16;
        int gblocks = (tiles + 3) / 4;
        long total4 = (long)N * 16;
        int iblocks = (int)((total4 + 255) / 256);
        k_setup<<<gblocks + iblocks, 256, 0, stream>>>(feat, W, bias, G, out, N, gblocks);

        const int cpw = 2;                       // 128 edges/wave -> 12500 waves (~8+/SIMD)
        int nchunks = (E + 63) / 64;
        int nwaves = (nchunks + cpw - 1) / cpw;
        int nblocks = (nwaves + 3) / 4;
        k_spmm<<<nblocks, 256, 0, stream>>>(G, erow, ecol, evalv, bias, out, E, cpw);
    } else {
        long total4 = (long)N * 16;
        k_init<<<(int)((total4 + 255) / 256), 256, 0, stream>>>(bias, out, total4);
        int epw = (E + 8191) / 8192;
        if (epw < 32) epw = 32;
        int nwaves = (E + epw - 1) / epw;
        int nblocks = (nwaves + 3) / 4;
        k_fused<<<nblocks, 256, 0, stream>>>(feat, erow, ecol, evalv, W, out, E, epw);
    }
}

// Round 8
// 139.710 us; speedup vs baseline: 1.7718x; 1.0136x over previous
//
#include <hip/hip_runtime.h>
#include <hip/hip_bf16.h>

typedef __attribute__((ext_vector_type(8))) short short8;
typedef __attribute__((ext_vector_type(4))) float f32x4;

__device__ __forceinline__ unsigned short f2bf(float x) {
    unsigned int u = __float_as_uint(x);
    unsigned int lsb = (u >> 16) & 1u;
    u += 0x7fffu + lsb;                    // round-to-nearest-even
    return (unsigned short)(u >> 16);
}

__device__ __forceinline__ float bf2f(unsigned int b16) {
    return __uint_as_float(b16 << 16);
}

__device__ __forceinline__ short8 pack8(f32x4 a, f32x4 b) {
    short8 r;
    r[0] = (short)f2bf(a.x); r[1] = (short)f2bf(a.y);
    r[2] = (short)f2bf(a.z); r[3] = (short)f2bf(a.w);
    r[4] = (short)f2bf(b.x); r[5] = (short)f2bf(b.y);
    r[6] = (short)f2bf(b.z); r[7] = (short)f2bf(b.w);
    return r;
}

// Standalone init (fallback path): out[n][c] = bias[c]
__global__ __launch_bounds__(256) void k_init(const float* __restrict__ bias,
                                              float* __restrict__ out, long total4) {
    long i4 = (long)blockIdx.x * 256 + threadIdx.x;
    if (i4 < total4) {
        const f32x4* b4 = (const f32x4*)bias;
        ((f32x4*)out)[i4] = b4[i4 & 15];
    }
}

// Fused: blocks [0,gblocks) compute G = (feat @ W.T) in bf16 via MFMA;
// blocks [gblocks, ...) broadcast bias into out.
// NOTE: out init must be a PLAIN store — NT store streamed it to HBM and made
// every later atomic flush RMW against HBM (R4: WRITE_SIZE doubled, +22 us).
__global__ __launch_bounds__(256) void k_setup(const float* __restrict__ feat,
                                               const float* __restrict__ W,
                                               const float* __restrict__ bias,
                                               unsigned short* __restrict__ G,
                                               float* __restrict__ out,
                                               int N, int gblocks) {
    if ((int)blockIdx.x >= gblocks) {
        long i4 = (long)(blockIdx.x - gblocks) * 256 + threadIdx.x;
        long total4 = (long)N * 16;            // N*64 floats / 4
        if (i4 < total4) {
            const f32x4* b4 = (const f32x4*)bias;
            ((f32x4*)out)[i4] = b4[i4 & 15];   // plain store: stay dirty in L2
        }
        return;
    }

    int wave = blockIdx.x * 4 + (threadIdx.x >> 6);
    int lane = threadIdx.x & 63;
    int m0 = wave * 16;
    if (m0 >= N) return;
    int n = lane & 15;
    int quad = lane >> 4;

    // B fragments: B[k][c0+n] = W[c0+n][k]; k = ks*32 + quad*8 + j
    short8 bf[4][2];
#pragma unroll
    for (int ct = 0; ct < 4; ++ct)
#pragma unroll
        for (int ks = 0; ks < 2; ++ks) {
            const f32x4* wp = (const f32x4*)(W + (size_t)(ct * 16 + n) * 64 + ks * 32 + quad * 8);
            f32x4 w0 = wp[0];
            f32x4 w1 = wp[1];
            bf[ct][ks] = pack8(w0, w1);
        }

    // A fragments: A[m0+n][k]  (NT load: feat read exactly once)
    int mrow = m0 + n; if (mrow >= N) mrow = N - 1;
    short8 af[2];
#pragma unroll
    for (int ks = 0; ks < 2; ++ks) {
        const f32x4* ap = (const f32x4*)(feat + (size_t)mrow * 64 + ks * 32 + quad * 8);
        f32x4 a0 = __builtin_nontemporal_load(ap);
        f32x4 a1 = __builtin_nontemporal_load(ap + 1);
        af[ks] = pack8(a0, a1);
    }

    f32x4 acc[4];
#pragma unroll
    for (int ct = 0; ct < 4; ++ct) {
        acc[ct] = (f32x4){0.f, 0.f, 0.f, 0.f};
#pragma unroll
        for (int ks = 0; ks < 2; ++ks)
            acc[ct] = __builtin_amdgcn_mfma_f32_16x16x32_bf16(af[ks], bf[ct][ks], acc[ct], 0, 0, 0);
    }

    // D layout: col = lane&15 (=n), row = quad*4 + reg. Plain stores: G is
    // re-read by k_spmm, keep it in L2/L3.
#pragma unroll
    for (int ct = 0; ct < 4; ++ct)
#pragma unroll
        for (int r = 0; r < 4; ++r) {
            int rowm = m0 + quad * 4 + r;
            if (rowm < N)
                G[(size_t)rowm * 64 + ct * 16 + n] = f2bf(acc[ct][r]);
        }
}

// SpMM: out[row] += val * G[col]. Sorted rows. 128 edges/wave.
// R8: software-pipelined gathers. All metadata loaded up front (6 NT vector
// loads); gather groups of 16 double-buffered: group j+1 issued BEFORE group
// j is consumed, so ~16-32 loads stay in flight through the consume phase
// (previous structure had 0 in flight during consume -> latency-bound).
// Raw ushort results buffered; bf16->f32 shift deferred to consume so the
// prefetch issue site needs no vmcnt wait.
// Flush: first/last rows may be shared across waves -> atomicAdd; interior
// rows are exclusively owned -> plain coalesced store out[row] = bias + acc.
__global__ __launch_bounds__(256) void k_spmm(const unsigned short* __restrict__ G,
                                              const int* __restrict__ erow,
                                              const int* __restrict__ ecol,
                                              const float* __restrict__ evalv,
                                              const float* __restrict__ bias,
                                              float* __restrict__ out, int E) {
    int wave = blockIdx.x * 4 + (threadIdx.x >> 6);
    int lane = threadIdx.x & 63;
    long base0 = (long)wave * 128;
    if (base0 >= E) return;

    float blane = bias[lane];
    int cur;
    float acc = 0.f;
    bool first = true;             // first flushed row may be shared w/ prev wave

    if (base0 + 128 <= E) {
        // ---- fast path: full 128-edge segment, fully unrolled pipeline ----
        long i0 = base0 + lane;
        int rv[2], cv[2], vv[2];
        rv[0] = __builtin_nontemporal_load(erow + i0);
        cv[0] = __builtin_nontemporal_load(ecol + i0);
        vv[0] = __float_as_int(__builtin_nontemporal_load(evalv + i0));
        rv[1] = __builtin_nontemporal_load(erow + i0 + 64);
        cv[1] = __builtin_nontemporal_load(ecol + i0 + 64);
        vv[1] = __float_as_int(__builtin_nontemporal_load(evalv + i0 + 64));

        cur = __builtin_amdgcn_readlane(rv[0], 0);

        unsigned g[2][16];          // raw ushort gather results (double buffer)
        // prologue: issue group 0
#pragma unroll
        for (int u = 0; u < 16; ++u) {
            int c = __builtin_amdgcn_readlane(cv[0], u);
            g[0][u] = G[((size_t)(unsigned)c << 6) | (unsigned)lane];
        }
#pragma unroll
        for (int j = 0; j < 8; ++j) {
            // issue group j+1 into the other buffer before consuming group j
            if (j < 7) {
                int chp = (j + 1) >> 2, jop = ((j + 1) & 3) * 16;
#pragma unroll
                for (int u = 0; u < 16; ++u) {
                    int c = __builtin_amdgcn_readlane(cv[chp], jop + u);
                    g[(j + 1) & 1][u] = G[((size_t)(unsigned)c << 6) | (unsigned)lane];
                }
            }
            int ch = j >> 2, jo = (j & 3) * 16;
#pragma unroll
            for (int u = 0; u < 16; ++u) {
                int r = __builtin_amdgcn_readlane(rv[ch], jo + u);   // SGPR
                float v = __int_as_float(__builtin_amdgcn_readlane(vv[ch], jo + u));
                if (r != cur) {                                       // scalar branch
                    if (first) {
                        atomicAdd(out + ((size_t)(unsigned)cur << 6) + lane, acc);
                        first = false;
                    } else {
                        out[((size_t)(unsigned)cur << 6) + lane] = blane + acc;
                    }
                    acc = 0.f;
                    cur = r;
                }
                acc = fmaf(v, bf2f(g[j & 1][u]), acc);
            }
        }
    } else {
        // ---- tail path: generic per-edge loop ----
        cur = __builtin_amdgcn_readfirstlane(erow[base0]);
        long e1 = E;
        for (long e = base0; e < e1; ++e) {
            int r = erow[e];
            int c = ecol[e];
            float v = evalv[e];
            float gg = bf2f(G[((size_t)(unsigned)c << 6) | (unsigned)lane]);
            if (r != cur) {
                if (first) {
                    atomicAdd(out + ((size_t)(unsigned)cur << 6) + lane, acc);
                    first = false;
                } else {
                    out[((size_t)(unsigned)cur << 6) + lane] = blane + acc;
                }
                acc = 0.f;
                cur = r;
            }
            acc = fmaf(v, gg, acc);
        }
    }

    // last row may be shared with the next wave -> always atomic
    atomicAdd(out + ((size_t)(unsigned)cur << 6) + lane, acc);
}

// Fallback if ws too small: fused f32 gather + shfl transform at flush.
__global__ __launch_bounds__(256) void k_fused(const float* __restrict__ feat,
                                               const int* __restrict__ erow,
                                               const int* __restrict__ ecol,
                                               const float* __restrict__ evalv,
                                               const float* __restrict__ W,
                                               float* __restrict__ out,
                                               int E, int epw) {
    __shared__ float Wt[64 * 64];
    for (int i = threadIdx.x; i < 4096; i += 256) {
        int c = i >> 6, f = i & 63;
        Wt[f * 64 + c] = W[i];
    }
    __syncthreads();

    int wave = blockIdx.x * 4 + (threadIdx.x >> 6);
    int lane = threadIdx.x & 63;
    long e0 = (long)wave * epw;
    if (e0 >= E) return;
    long e1 = e0 + epw; if (e1 > E) e1 = E;

    int cur = erow[e0];
    float acc = 0.f;
    for (long e = e0; e < e1; ++e) {
        int r = erow[e];
        int c = ecol[e];
        float v = evalv[e];
        float g = feat[((size_t)c << 6) | lane];
        if (r != cur) {
            float res = 0.f;
#pragma unroll
            for (int f = 0; f < 64; ++f)
                res += __shfl(acc, f, 64) * Wt[f * 64 + lane];
            atomicAdd(out + ((size_t)cur << 6) + lane, res);
            acc = 0.f;
            cur = r;
        }
        acc += v * g;
    }
    {
        float res = 0.f;
#pragma unroll
        for (int f = 0; f < 64; ++f)
            res += __shfl(acc, f, 64) * Wt[f * 64 + lane];
        atomicAdd(out + ((size_t)cur << 6) + lane, res);
    }
}

extern "C" void kernel_launch(void* const* d_in, const int* in_sizes, int n_in,
                              void* d_out, int out_size, void* d_ws, size_t ws_size,
                              hipStream_t stream) {
    const float* feat  = (const float*)d_in[0];
    const int*   erow  = (const int*)d_in[1];
    const int*   ecol  = (const int*)d_in[2];
    const float* evalv = (const float*)d_in[3];
    const float* W     = (const float*)d_in[4];
    const float* bias  = (const float*)d_in[5];
    float* out = (float*)d_out;

    int N = in_sizes[0] / 64;
    int E = in_sizes[1];

    size_t need = (size_t)N * 64 * sizeof(unsigned short);
    if (ws_size >= need) {
        unsigned short* G = (unsigned short*)d_ws;
        int tiles = (N + 15) / 16;
        int gblocks = (tiles + 3) / 4;
        long total4 = (long)N * 16;
        int iblocks = (int)((total4 + 255) / 256);
        k_setup<<<gblocks + iblocks, 256, 0, stream>>>(feat, W, bias, G, out, N, gblocks);

        int nwaves = (E + 127) / 128;            // 128 edges/wave
        int nblocks = (nwaves + 3) / 4;
        k_spmm<<<nblocks, 256, 0, stream>>>(G, erow, ecol, evalv, bias, out, E);
    } else {
        long total4 = (long)N * 16;
        k_init<<<(int)((total4 + 255) / 256), 256, 0, stream>>>(bias, out, total4);
        int epw = (E + 8191) / 8192;
        if (epw < 32) epw = 32;
        int nwaves = (E + epw - 1) / epw;
        int nblocks = (nwaves + 3) / 4;
        k_fused<<<nblocks, 256, 0, stream>>>(feat, erow, ecol, evalv, W, out, E, epw);
    }
}